// Round 7
// baseline (111.783 us; speedup 1.0000x reference)
//
#include <hip/hip_runtime.h>
#include <cstdint>

#define IN_F   4096
#define OUT_F  14336
#define GROUP  128
#define KROT   8
#define BATCH  16
#define NJP    1792           // packed words per weight row
#define NG     32             // quant groups

typedef __attribute__((ext_vector_type(8))) short short8;  // 8 bf16
typedef __attribute__((ext_vector_type(4))) float f32x4;

// Module-scope scratch (no d_ws dependence).
__device__ uint32_t g_xa[BATCH * IN_F / 2];    // rotated activations, bf16 pairs
__device__ float    g_part[4 * BATCH * OUT_F]; // 4 K-chunk fp32 partials

static __device__ __forceinline__ unsigned short f2bf(float f) {
    union { float f; uint32_t i; } v; v.f = f;
    uint32_t u = v.i;
    uint32_t r = u + 0x7FFFu + ((u >> 16) & 1u);  // RNE
    return (unsigned short)(r >> 16);
}

// ---------------------------------------------------------------------------
// Kernel 1: rotation layers + bf16 pack (unchanged from round 6 — verified).
// ---------------------------------------------------------------------------
__global__ __launch_bounds__(1024) void k_rotate(
    const float* __restrict__ x,      // [16][4096] f32 (fp16 promoted)
    const float* __restrict__ theta,  // [8][2048]  f32
    const int*   __restrict__ pairs,  // [8][4096]  int32
    const float* __restrict__ cscale) // [4096]     f32
{
    __shared__ float row[IN_F];
    const int b   = blockIdx.x;
    const int tid = threadIdx.x;

    int2  ij0[KROT], ij1[KROT];
    float c0[KROT], s0[KROT], c1[KROT], s1[KROT];
#pragma unroll
    for (int k = 0; k < KROT; ++k) {
        const int2*  pk = (const int2*)(pairs + k * IN_F);
        const float* tk = theta + k * (IN_F / 2);
        ij0[k] = pk[tid];
        ij1[k] = pk[tid + 1024];
        __sincosf(tk[tid],        &s0[k], &c0[k]);
        __sincosf(tk[tid + 1024], &s1[k], &c1[k]);
    }

    for (int i = tid; i < IN_F; i += 1024) row[i] = x[b * IN_F + i];
    __syncthreads();

#pragma unroll
    for (int k = 0; k < KROT; ++k) {
        float a0 = row[ij0[k].x], b0 = row[ij0[k].y];
        float a1 = row[ij1[k].x], b1 = row[ij1[k].y];
        row[ij0[k].x] = c0[k] * a0 - s0[k] * b0;
        row[ij0[k].y] = s0[k] * a0 + c0[k] * b0;
        row[ij1[k].x] = c1[k] * a1 - s1[k] * b1;
        row[ij1[k].y] = s1[k] * a1 + c1[k] * b1;
        __syncthreads();
    }

    for (int i = tid; i < IN_F / 2; i += 1024) {
        float v0 = row[2 * i]     * cscale[2 * i];
        float v1 = row[2 * i + 1] * cscale[2 * i + 1];
        g_xa[b * (IN_F / 2) + i] =
            (uint32_t)f2bf(v0) | ((uint32_t)f2bf(v1) << 16);
    }
}

// ---------------------------------------------------------------------------
// Kernel 2: MFMA dequant-GEMM, software-pipelined. Round-6 structure issued
// stage-st loads AFTER the stage-(st-1) barrier -> exposed latency. Now stage
// st+1's qweight/qzeros/A-frag loads issue at the TOP of stage st (a full
// stage of dequant+barrier+MFMA in front of them). Single proven LDS tile.
// ---------------------------------------------------------------------------
__global__ __launch_bounds__(256) void k_gemm(
    const int*   __restrict__ qweight, // [4096][1792] int32
    const int*   __restrict__ qzeros,  // [32][1792]   int32
    const float* __restrict__ scales)  // [32][14336]  f32
{
    __shared__ uint4 ldsb[128 * 17];   // [128 n][16 k-octet cells + 1 pad]

    const int tid   = threadIdx.x;
    const int bn    = blockIdx.x % 112;
    const int bk    = blockIdx.x / 112;       // K-chunk 0..3
    const int n0    = bn * 128;
    const int jp0   = n0 >> 3;
    const int jp    = tid & 15;               // word lane 0..15
    const int koct  = tid >> 4;               // k-octet 0..15
    const int lane  = tid & 63;
    const int wv    = tid >> 6;
    const int mrow  = lane & 15;
    const int quad  = lane >> 4;
    const int xsw   = koct ^ (jp & 7);

    f32x4 m0 = {0.f, 0.f, 0.f, 0.f};
    f32x4 m1 = {0.f, 0.f, 0.f, 0.f};

    const int nl0 = wv * 32 + mrow;
    const int nl1 = nl0 + 16;
    const int sw0 = (nl0 >> 3) & 7;
    const int sw1 = (nl1 >> 3) & 7;

    const int*      qwp = qweight + jp0 + jp;
    const uint32_t* ap  = g_xa + mrow * (IN_F / 2) + bk * 512 + quad * 4;

    // ---- prefetch stage 0 ----
    uint32_t wc[8], zc;
    uint4    ac[4];
    {
        const size_t kr0 = (size_t)(bk * 8 + 0) * GROUP + koct * 8;
#pragma unroll
        for (int i = 0; i < 8; ++i) wc[i] = (uint32_t)qwp[(kr0 + i) * NJP];
        zc = (uint32_t)qzeros[(size_t)(bk * 8) * NJP + jp0 + jp];
#pragma unroll
        for (int kt = 0; kt < 4; ++kt) ac[kt] = *(const uint4*)(ap + kt * 16);
    }

    for (int st = 0; st < 8; ++st) {
        const int g = bk * 8 + st;

        // ---- issue stage st+1 loads first (in flight through this stage) --
        uint32_t wn[8], zn;
        uint4    an[4];
        if (st < 7) {
            const size_t kr1 = (size_t)(g + 1) * GROUP + koct * 8;
#pragma unroll
            for (int i = 0; i < 8; ++i) wn[i] = (uint32_t)qwp[(kr1 + i) * NJP];
            zn = (uint32_t)qzeros[(size_t)(g + 1) * NJP + jp0 + jp];
            const uint32_t* apn = ap + (st + 1) * 64;
#pragma unroll
            for (int kt = 0; kt < 4; ++kt) an[kt] = *(const uint4*)(apn + kt * 16);
        }

        // ---- dequant current stage -> LDS (exact bf16 pack of iw-iz) ------
#pragma unroll
        for (int c = 0; c < 8; ++c) {
            const int iz = (int)((zc >> (4 * c)) & 15u);
            uint4 cell;
            uint32_t pk[4];
#pragma unroll
            for (int h = 0; h < 4; ++h) {
                union { float f; uint32_t u; } a, b;
                a.f = (float)((int)((wc[2 * h]     >> (4 * c)) & 15u) - iz);
                b.f = (float)((int)((wc[2 * h + 1] >> (4 * c)) & 15u) - iz);
                pk[h] = (a.u >> 16) | (b.u & 0xFFFF0000u);
            }
            cell.x = pk[0]; cell.y = pk[1]; cell.z = pk[2]; cell.w = pk[3];
            ldsb[(jp * 8 + c) * 17 + xsw] = cell;
        }
        __syncthreads();

        // ---- MFMA from LDS (B) + registers (A) ----------------------------
        f32x4 ga = {0.f, 0.f, 0.f, 0.f};
        f32x4 gb = {0.f, 0.f, 0.f, 0.f};
#pragma unroll
        for (int kt = 0; kt < 4; ++kt) {
            union { uint4 q; short8 s; } af, b0, b1;
            af.q = ac[kt];
            const int ko = kt * 4 + quad;
            b0.q = ldsb[nl0 * 17 + (ko ^ sw0)];
            b1.q = ldsb[nl1 * 17 + (ko ^ sw1)];
            ga = __builtin_amdgcn_mfma_f32_16x16x32_bf16(af.s, b0.s, ga, 0, 0, 0);
            gb = __builtin_amdgcn_mfma_f32_16x16x32_bf16(af.s, b1.s, gb, 0, 0, 0);
        }
        const float s0 = scales[(size_t)g * OUT_F + n0 + nl0];
        const float s1 = scales[(size_t)g * OUT_F + n0 + nl1];
        m0 += s0 * ga;
        m1 += s1 * gb;
        __syncthreads();

        // ---- rotate pipeline registers ------------------------------------
        if (st < 7) {
#pragma unroll
            for (int i = 0; i < 8; ++i) wc[i] = wn[i];
            zc = zn;
#pragma unroll
            for (int kt = 0; kt < 4; ++kt) ac[kt] = an[kt];
        }
    }

    // epilogue: C/D layout col=lane&15, row=quad*4+reg
    float* pp = g_part + (size_t)bk * BATCH * OUT_F;
#pragma unroll
    for (int r = 0; r < 4; ++r) {
        const int row = quad * 4 + r;
        pp[(size_t)row * OUT_F + n0 + nl0] = m0[r];
        pp[(size_t)row * OUT_F + n0 + nl1] = m1[r];
    }
}

// ---------------------------------------------------------------------------
// Kernel 3: sum the 4 K-chunk partials -> d_out. float4 per thread.
// ---------------------------------------------------------------------------
__global__ __launch_bounds__(128) void k_reduce(float* __restrict__ out)
{
    const int t = blockIdx.x * 128 + threadIdx.x;   // 0..57343
    const size_t j = (size_t)t * 4;
    float4 a = *(const float4*)(g_part + j);
    float4 b = *(const float4*)(g_part + (size_t)BATCH * OUT_F + j);
    float4 c = *(const float4*)(g_part + (size_t)2 * BATCH * OUT_F + j);
    float4 d = *(const float4*)(g_part + (size_t)3 * BATCH * OUT_F + j);
    float4 s;
    s.x = (a.x + b.x) + (c.x + d.x);
    s.y = (a.y + b.y) + (c.y + d.y);
    s.z = (a.z + b.z) + (c.z + d.z);
    s.w = (a.w + b.w) + (c.w + d.w);
    *(float4*)(out + j) = s;
}

extern "C" void kernel_launch(void* const* d_in, const int* in_sizes, int n_in,
                              void* d_out, int out_size, void* d_ws, size_t ws_size,
                              hipStream_t stream) {
    const float* x       = (const float*)d_in[0];
    const float* theta   = (const float*)d_in[1];
    const int*   pairs   = (const int*)d_in[2];
    const float* cscale  = (const float*)d_in[3];
    const int*   qweight = (const int*)d_in[4];
    const int*   qzeros  = (const int*)d_in[5];
    const float* scales  = (const float*)d_in[6];
    float*       out     = (float*)d_out;
    (void)d_ws; (void)ws_size;

    k_rotate<<<16, 1024, 0, stream>>>(x, theta, pairs, cscale);
    k_gemm<<<448, 256, 0, stream>>>(qweight, qzeros, scales);
    k_reduce<<<(BATCH * OUT_F) / (128 * 4), 128, 0, stream>>>(out);
}

// Round 8
// 107.555 us; speedup vs baseline: 1.0393x; 1.0393x over previous
//
#include <hip/hip_runtime.h>
#include <cstdint>

#define IN_F   4096
#define OUT_F  14336
#define GROUP  128
#define KROT   8
#define BATCH  16
#define NJP    1792           // packed words per weight row
#define NG     32             // quant groups

typedef __attribute__((ext_vector_type(8))) short short8;  // 8 bf16
typedef __attribute__((ext_vector_type(4))) float f32x4;

// Module-scope scratch (no d_ws dependence).
__device__ uint32_t g_xa[BATCH * IN_F / 2];    // rotated activations, bf16 pairs
__device__ float    g_rs[NG * BATCH];          // per-(group,row) sums of bf16 acts
__device__ float    g_part[4 * BATCH * OUT_F]; // 4 K-chunk fp32 partials

static __device__ __forceinline__ unsigned short f2bf(float f) {
    union { float f; uint32_t i; } v; v.f = f;
    uint32_t u = v.i;
    uint32_t r = u + 0x7FFFu + ((u >> 16) & 1u);  // RNE
    return (unsigned short)(r >> 16);
}
static __device__ __forceinline__ float bf2f(uint32_t u16) {
    union { uint32_t i; float f; } v; v.i = u16 << 16; return v.f;
}

// ---------------------------------------------------------------------------
// Kernel 1: rotation layers + bf16 pack + per-group row-sums of the ROUNDED
// bf16 values (must match MFMA operands bit-exactly for the zero-point
// correction identity: sum_k a*(iw-iz) = sum_k a*(128+iw) - (128+iz)*sum_k a).
// Wave w's elements {2i,2i+1 : i=tid} lie entirely in group w (i=tid+1024 ->
// group 16+w), so a 64-lane shuffle reduction yields g_rs directly.
// ---------------------------------------------------------------------------
__global__ __launch_bounds__(1024) void k_rotate(
    const float* __restrict__ x,      // [16][4096] f32 (fp16 promoted)
    const float* __restrict__ theta,  // [8][2048]  f32
    const int*   __restrict__ pairs,  // [8][4096]  int32
    const float* __restrict__ cscale) // [4096]     f32
{
    __shared__ float row[IN_F];
    const int b   = blockIdx.x;
    const int tid = threadIdx.x;

    int2  ij0[KROT], ij1[KROT];
    float c0[KROT], s0[KROT], c1[KROT], s1[KROT];
#pragma unroll
    for (int k = 0; k < KROT; ++k) {
        const int2*  pk = (const int2*)(pairs + k * IN_F);
        const float* tk = theta + k * (IN_F / 2);
        ij0[k] = pk[tid];
        ij1[k] = pk[tid + 1024];
        __sincosf(tk[tid],        &s0[k], &c0[k]);
        __sincosf(tk[tid + 1024], &s1[k], &c1[k]);
    }

    for (int i = tid; i < IN_F; i += 1024) row[i] = x[b * IN_F + i];
    __syncthreads();

#pragma unroll
    for (int k = 0; k < KROT; ++k) {
        float a0 = row[ij0[k].x], b0 = row[ij0[k].y];
        float a1 = row[ij1[k].x], b1 = row[ij1[k].y];
        row[ij0[k].x] = c0[k] * a0 - s0[k] * b0;
        row[ij0[k].y] = s0[k] * a0 + c0[k] * b0;
        row[ij1[k].x] = c1[k] * a1 - s1[k] * b1;
        row[ij1[k].y] = s1[k] * a1 + c1[k] * b1;
        __syncthreads();
    }

    float p0, p1;
    {   // i = tid -> group (tid>>6); i = tid+1024 -> group 16+(tid>>6)
        int i = tid;
        uint32_t lo = f2bf(row[2 * i]     * cscale[2 * i]);
        uint32_t hi = f2bf(row[2 * i + 1] * cscale[2 * i + 1]);
        g_xa[b * (IN_F / 2) + i] = lo | (hi << 16);
        p0 = bf2f(lo) + bf2f(hi);
        i = tid + 1024;
        lo = f2bf(row[2 * i]     * cscale[2 * i]);
        hi = f2bf(row[2 * i + 1] * cscale[2 * i + 1]);
        g_xa[b * (IN_F / 2) + i] = lo | (hi << 16);
        p1 = bf2f(lo) + bf2f(hi);
    }
#pragma unroll
    for (int m = 1; m < 64; m <<= 1) {
        p0 += __shfl_xor(p0, m, 64);
        p1 += __shfl_xor(p1, m, 64);
    }
    if ((tid & 63) == 0) {
        const int w = tid >> 6;
        g_rs[w * BATCH + b]        = p0;
        g_rs[(16 + w) * BATCH + b] = p1;
    }
}

// ---------------------------------------------------------------------------
// Kernel 2: MFMA dequant-GEMM. Dequant is now pure bit-ops: 0x4300|v IS
// bf16(128+v) exactly (exp 2^7, mantissa ulp 1) -> no cvt/sub per nibble.
// Zero-point folded per GROUP in the epilogue of each stage:
//   m += s*ga - s*(128+iz)*rowsum.  Scales/zeros/rowsums prologue-hoisted.
// (R7 lesson: explicit load pipelining is neutral -> simple R6 load order.)
// ---------------------------------------------------------------------------
__global__ __launch_bounds__(256) void k_gemm(
    const int*   __restrict__ qweight, // [4096][1792] int32
    const int*   __restrict__ qzeros,  // [32][1792]   int32
    const float* __restrict__ scales)  // [32][14336]  f32
{
    __shared__ uint4 ldsb[128 * 17];   // [128 n][16 k-octet cells + 1 pad]

    const int tid   = threadIdx.x;
    const int bn    = blockIdx.x % 112;
    const int bk    = blockIdx.x / 112;       // K-chunk 0..3
    const int n0    = bn * 128;
    const int jp0   = n0 >> 3;
    const int jp    = tid & 15;               // word lane 0..15
    const int koct  = tid >> 4;               // k-octet 0..15
    const int lane  = tid & 63;
    const int wv    = tid >> 6;
    const int mrow  = lane & 15;
    const int quad  = lane >> 4;
    const int xsw   = koct ^ (jp & 7);

    const int nl0 = wv * 32 + mrow;
    const int nl1 = nl0 + 16;
    const int sw0 = (nl0 >> 3) & 7;
    const int sw1 = (nl1 >> 3) & 7;

    // ---- prologue: hoist scales, zero-points, row-sums into registers ----
    float s0v[8], s1v[8], zf0[8], zf1[8];
    f32x4 rsv[8];
    {
        const int jz0 = jp0 + (nl0 >> 3);
        const int jz1 = jp0 + (nl1 >> 3);
        const int sh  = 4 * (mrow & 7);       // (n0+nl0)&7 == (n0+nl1)&7 == mrow&7
#pragma unroll
        for (int g = 0; g < 8; ++g) {
            const int gg = bk * 8 + g;
            s0v[g] = scales[(size_t)gg * OUT_F + n0 + nl0];
            s1v[g] = scales[(size_t)gg * OUT_F + n0 + nl1];
            zf0[g] = 128.0f + (float)(((uint32_t)qzeros[gg * NJP + jz0] >> sh) & 15u);
            zf1[g] = 128.0f + (float)(((uint32_t)qzeros[gg * NJP + jz1] >> sh) & 15u);
            rsv[g] = *(const f32x4*)(g_rs + gg * BATCH + quad * 4);
        }
    }

    f32x4 m0 = {0.f, 0.f, 0.f, 0.f};
    f32x4 m1 = {0.f, 0.f, 0.f, 0.f};

    for (int st = 0; st < 8; ++st) {
        const int g   = bk * 8 + st;
        const int kr0 = g * GROUP + koct * 8;

        uint32_t wc[8];
#pragma unroll
        for (int i = 0; i < 8; ++i)
            wc[i] = (uint32_t)qweight[(size_t)(kr0 + i) * NJP + jp0 + jp];

        uint4 ac[4];
        const uint32_t* apst = g_xa + mrow * (IN_F / 2) + bk * 512 + st * 64 + quad * 4;
#pragma unroll
        for (int kt = 0; kt < 4; ++kt) ac[kt] = *(const uint4*)(apst + kt * 16);

        // dequant: bf16(128+v) by bit-OR only
#pragma unroll
        for (int c = 0; c < 8; ++c) {
            uint4 cell;
            uint32_t pk[4];
#pragma unroll
            for (int h = 0; h < 4; ++h) {
                uint32_t lo = (wc[2 * h]     >> (4 * c)) & 15u;
                uint32_t hi = (wc[2 * h + 1] >> (4 * c)) & 15u;
                pk[h] = 0x43004300u | lo | (hi << 16);
            }
            cell.x = pk[0]; cell.y = pk[1]; cell.z = pk[2]; cell.w = pk[3];
            ldsb[(jp * 8 + c) * 17 + xsw] = cell;
        }
        __syncthreads();

        f32x4 ga = {0.f, 0.f, 0.f, 0.f};
        f32x4 gb = {0.f, 0.f, 0.f, 0.f};
#pragma unroll
        for (int kt = 0; kt < 4; ++kt) {
            union { uint4 q; short8 s; } af, b0, b1;
            af.q = ac[kt];
            const int ko = kt * 4 + quad;
            b0.q = ldsb[nl0 * 17 + (ko ^ sw0)];
            b1.q = ldsb[nl1 * 17 + (ko ^ sw1)];
            ga = __builtin_amdgcn_mfma_f32_16x16x32_bf16(af.s, b0.s, ga, 0, 0, 0);
            gb = __builtin_amdgcn_mfma_f32_16x16x32_bf16(af.s, b1.s, gb, 0, 0, 0);
        }

        // per-group fold: m += s*ga - (s*(128+iz))*rowsum
        const float t0 = s0v[st] * zf0[st];
        const float t1 = s1v[st] * zf1[st];
#pragma unroll
        for (int r = 0; r < 4; ++r) {
            m0[r] = fmaf(s0v[st], ga[r], fmaf(-t0, rsv[st][r], m0[r]));
            m1[r] = fmaf(s1v[st], gb[r], fmaf(-t1, rsv[st][r], m1[r]));
        }
        __syncthreads();
    }

    // epilogue: C/D layout col=lane&15, row=quad*4+reg
    float* pp = g_part + (size_t)bk * BATCH * OUT_F;
#pragma unroll
    for (int r = 0; r < 4; ++r) {
        const int row = quad * 4 + r;
        pp[(size_t)row * OUT_F + n0 + nl0] = m0[r];
        pp[(size_t)row * OUT_F + n0 + nl1] = m1[r];
    }
}

// ---------------------------------------------------------------------------
// Kernel 3: sum the 4 K-chunk partials -> d_out. float4 per thread.
// ---------------------------------------------------------------------------
__global__ __launch_bounds__(128) void k_reduce(float* __restrict__ out)
{
    const int t = blockIdx.x * 128 + threadIdx.x;   // 0..57343
    const size_t j = (size_t)t * 4;
    float4 a = *(const float4*)(g_part + j);
    float4 b = *(const float4*)(g_part + (size_t)BATCH * OUT_F + j);
    float4 c = *(const float4*)(g_part + (size_t)2 * BATCH * OUT_F + j);
    float4 d = *(const float4*)(g_part + (size_t)3 * BATCH * OUT_F + j);
    float4 s;
    s.x = (a.x + b.x) + (c.x + d.x);
    s.y = (a.y + b.y) + (c.y + d.y);
    s.z = (a.z + b.z) + (c.z + d.z);
    s.w = (a.w + b.w) + (c.w + d.w);
    *(float4*)(out + j) = s;
}

extern "C" void kernel_launch(void* const* d_in, const int* in_sizes, int n_in,
                              void* d_out, int out_size, void* d_ws, size_t ws_size,
                              hipStream_t stream) {
    const float* x       = (const float*)d_in[0];
    const float* theta   = (const float*)d_in[1];
    const int*   pairs   = (const int*)d_in[2];
    const float* cscale  = (const float*)d_in[3];
    const int*   qweight = (const int*)d_in[4];
    const int*   qzeros  = (const int*)d_in[5];
    const float* scales  = (const float*)d_in[6];
    float*       out     = (float*)d_out;
    (void)d_ws; (void)ws_size;

    k_rotate<<<16, 1024, 0, stream>>>(x, theta, pairs, cscale);
    k_gemm<<<448, 256, 0, stream>>>(qweight, qzeros, scales);
    k_reduce<<<(BATCH * OUT_F) / (128 * 4), 128, 0, stream>>>(out);
}